// Round 3
// baseline (47.650 us; speedup 1.0000x reference)
//
#include <hip/hip_runtime.h>

#define H     128
#define W     128
#define HO    126
#define WO    126
#define NPIX  (HO * WO)          // 15876
#define QROWS 32                 // output rows per block (last quarter: 30)
#define TROWS 34                 // max staged input rows
#define TSZ   (TROWS * W + 8)    // + pad for tail float2 reads

// f4-slot swizzle (involution) to spread LDS banks on the b128 reads.
__device__ __forceinline__ int sw(int j) { return j ^ ((j >> 3) & 1); }

__global__ __launch_bounds__(1024) void zero_out(float* __restrict__ out) {
    out[threadIdx.x] = 0.f;
}

// One block per (plane, quarter): stage 32..34 input rows in LDS, compute
// 3x3 window stats for 30..32 output rows, atomicAdd partial mean.
__global__ __launch_bounds__(256, 8) void bp_kernel(const float* __restrict__ x,
                                                    float* __restrict__ out) {
    __shared__ float tile[TSZ];
    __shared__ float wsum[4];

    const int bid   = blockIdx.x;
    const int plane = bid >> 2;
    const int q     = bid & 3;
    const int R0    = q * QROWS;
    const int orows = (q == 3) ? 30 : 32;
    const int irows = orows + 2;
    const int tid   = threadIdx.x;

    const float4* src4 = (const float4*)(x + (size_t)plane * (H * W)) + R0 * 32;

    // ---- stage irows rows into LDS (swizzled f4 slots), coalesced ----
    float4* t4 = (float4*)tile;
    for (int i = tid; i < irows * 32; i += 256) {
        const int row = i >> 5, j = i & 31;
        t4[row * 32 + sw(j)] = src4[row * 32 + j];
    }
    if (tid < 8) tile[TROWS * W + tid] = 0.f;
    __syncthreads();

    float acc = 0.f;

    // orows x 16 groups of 8 pixels (2 iterations per thread)
    for (int g = tid; g < orows * 16; g += 256) {
        const int y  = g >> 4;
        const int xq = g & 15;
        const int jb = xq << 1;
        const int s0 = sw(jb) << 2;
        const int s1 = sw(jb + 1) << 2;
        const int s2 = sw(jb + 2) << 2;    // xq=15 -> 128 (next-row/pad; masked px only)

        float r[3][10];
#pragma unroll
        for (int dr = 0; dr < 3; ++dr) {
            const float* rowp = &tile[(y + dr) * W];
            const float4 a = *(const float4*)(rowp + s0);
            const float4 b = *(const float4*)(rowp + s1);
            const float2 e = *(const float2*)(rowp + s2);
            r[dr][0] = a.x; r[dr][1] = a.y; r[dr][2] = a.z; r[dr][3] = a.w;
            r[dr][4] = b.x; r[dr][5] = b.y; r[dr][6] = b.z; r[dr][7] = b.w;
            r[dr][8] = e.x; r[dr][9] = e.y;
        }

        float colsum[10], colss[10], colmax[10];
#pragma unroll
        for (int c = 0; c < 10; ++c) {
            colsum[c] = r[0][c] + r[1][c] + r[2][c];
            colss[c]  = fmaf(r[0][c], r[0][c], fmaf(r[1][c], r[1][c], r[2][c] * r[2][c]));
            colmax[c] = fmaxf(r[0][c], fmaxf(r[1][c], r[2][c]));   // -> v_max3
        }

        const bool full = (xq < 15);
#pragma unroll
        for (int k = 0; k < 8; ++k) {
            const float ctr  = r[1][k + 1];
            const float sum  = colsum[k] + colsum[k + 1] + colsum[k + 2];
            const float ss   = colss[k]  + colss[k + 1]  + colss[k + 2];
            const float wmax = fmaxf(colmax[k], fmaxf(colmax[k + 1], colmax[k + 2]));

            // sad over 8 non-center taps, pairwise tree (short dep chain)
            const float s01 = fabsf(r[0][k]     - ctr) + fabsf(r[0][k + 1] - ctr);
            const float s23 = fabsf(r[0][k + 2] - ctr) + fabsf(r[1][k]     - ctr);
            const float s45 = fabsf(r[1][k + 2] - ctr) + fabsf(r[2][k]     - ctr);
            const float s67 = fabsf(r[2][k + 1] - ctr) + fabsf(r[2][k + 2] - ctr);
            const float sad = (s01 + s23) + (s45 + s67);

            const float cth = fmaf(sad, 1.f / 9.f, ctr);

            int bvi = (sad <= 0.f) ? 1 : 0;            // center: (0 >= thr)
#pragma unroll
            for (int i = 0; i < 3; ++i)
#pragma unroll
                for (int j = 0; j < 3; ++j)
                    if (!(i == 1 && j == 1))
                        bvi += (r[i][k + j] >= cth) ? 1 : 0;
            const float bv = (float)bvi;

            const float var9 = fmaf(sum, -sum, 9.f * ss);       // 81*var
            const float sd9  = __builtin_amdgcn_sqrtf(fmaxf(var9, 0.f)); // 9*std
            const float nf   = fmaf(sum, -1.f / 2295.f, bv * (1.f / 255.f));
            const float bn   = fmaf(nf, fmaf(sd9, 1.f / 9.f, -wmax), wmax);

            acc += (k < 6 || full) ? bn : 0.f;   // k<6 folds to unconditional
        }
    }

    // ---- block reduction + atomic combine ----
#pragma unroll
    for (int off = 32; off > 0; off >>= 1)
        acc += __shfl_down(acc, off, 64);
    if ((tid & 63) == 0) wsum[tid >> 6] = acc;
    __syncthreads();
    if (tid == 0)
        atomicAdd(out + plane,
                  (wsum[0] + wsum[1] + wsum[2] + wsum[3]) * (1.f / NPIX));
}

extern "C" void kernel_launch(void* const* d_in, const int* in_sizes, int n_in,
                              void* d_out, int out_size, void* d_ws, size_t ws_size,
                              hipStream_t stream) {
    const float* x = (const float*)d_in[0];
    float* out = (float*)d_out;
    zero_out<<<dim3(1), dim3(1024), 0, stream>>>(out);
    bp_kernel<<<dim3(16 * 64 * 4), dim3(256), 0, stream>>>(x, out);
}

// Round 4
// 42.769 us; speedup vs baseline: 1.1141x; 1.1141x over previous
//
#include <hip/hip_runtime.h>

#define H     128
#define W     128
#define HO    126
#define WO    126
#define NPIX  (HO * WO)          // 15876
#define QROWS 32                 // output rows per block (last quarter: 30)
#define TROWS 34                 // max staged input rows
#define TSZ   (TROWS * W + 8)    // + pad: tail float2 may touch 2 floats past row 33

__global__ __launch_bounds__(1024) void zero_out(float* __restrict__ out) {
    out[threadIdx.x] = 0.f;
}

// One block per (plane, quarter). 4-pixel groups keep the live set (~55 floats)
// inside the VGPR budget at 6 blocks/CU -> no spills, no mid-loop LDS reloads.
__global__ __launch_bounds__(256, 6) void bp_kernel(const float* __restrict__ x,
                                                    float* __restrict__ out) {
    __shared__ float tile[TSZ];
    __shared__ float wsum[4];

    const int bid   = blockIdx.x;
    const int plane = bid >> 2;
    const int q     = bid & 3;
    const int orows = (q == 3) ? 30 : 32;
    const int irows = orows + 2;
    const int tid   = threadIdx.x;

    // ---- stage input rows (linear, coalesced; consecutive lanes -> no conflicts) ----
    const float4* src4 = (const float4*)(x + (size_t)plane * (H * W)) + (q * QROWS) * 32;
    float4* t4 = (float4*)tile;
    for (int i = tid; i < irows * 32; i += 256)
        t4[i] = src4[i];
    __syncthreads();

    float acc = 0.f;
    const int ng = orows * 32;           // 4-px groups: 32 per output row

#pragma unroll 1
    for (int g = tid; g < ng; g += 256) {
        const int y  = g >> 5;
        const int xq = g & 31;
        const int x0 = xq << 2;

        float r[3][6];
#pragma unroll
        for (int dr = 0; dr < 3; ++dr) {
            const float* rowp = &tile[(y + dr) * W + x0];
            const float4 a = *(const float4*)rowp;       // cols x0..x0+3
            const float2 b = *(const float2*)(rowp + 4); // cols x0+4..x0+5 (garbage at xq=31 -> masked px only)
            r[dr][0] = a.x; r[dr][1] = a.y; r[dr][2] = a.z; r[dr][3] = a.w;
            r[dr][4] = b.x; r[dr][5] = b.y;
        }

        float cs[6], cq[6], cm[6];
#pragma unroll
        for (int c = 0; c < 6; ++c) {
            cs[c] = r[0][c] + r[1][c] + r[2][c];
            cq[c] = fmaf(r[0][c], r[0][c], fmaf(r[1][c], r[1][c], r[2][c] * r[2][c]));
            cm[c] = fmaxf(r[0][c], fmaxf(r[1][c], r[2][c]));    // -> v_max3
        }

#pragma unroll
        for (int k = 0; k < 4; ++k) {
            const float ctr  = r[1][k + 1];
            const float sum  = cs[k] + cs[k + 1] + cs[k + 2];
            const float ss   = cq[k] + cq[k + 1] + cq[k + 2];
            const float wmax = fmaxf(cm[k], fmaxf(cm[k + 1], cm[k + 2]));

            // diffs shared between sad and the compares
            float d[8];
            d[0] = r[0][k]     - ctr;  d[1] = r[0][k + 1] - ctr;
            d[2] = r[0][k + 2] - ctr;  d[3] = r[1][k]     - ctr;
            d[4] = r[1][k + 2] - ctr;  d[5] = r[2][k]     - ctr;
            d[6] = r[2][k + 1] - ctr;  d[7] = r[2][k + 2] - ctr;

            const float sad = ((fabsf(d[0]) + fabsf(d[1])) + (fabsf(d[2]) + fabsf(d[3])))
                            + ((fabsf(d[4]) + fabsf(d[5])) + (fabsf(d[6]) + fabsf(d[7])));
            const float thr = sad * (1.f / 9.f);

            int bvi = (sad <= 0.f) ? 1 : 0;    // center tap: 0 >= thr
#pragma unroll
            for (int t = 0; t < 8; ++t)
                bvi += (d[t] >= thr) ? 1 : 0;
            const float bv = (float)bvi;

            const float var9 = fmaf(sum, -sum, 9.f * ss);               // 81*var
            const float sd9  = __builtin_amdgcn_sqrtf(fmaxf(var9, 0.f)); // 9*std
            const float nf   = fmaf(sum, -1.f / 2295.f, bv * (1.f / 255.f));
            const float bn   = fmaf(nf, fmaf(sd9, 1.f / 9.f, -wmax), wmax);

            acc += (x0 + k < WO) ? bn : 0.f;
        }
    }

    // ---- block reduction + atomic combine across the 4 quarter-blocks ----
#pragma unroll
    for (int off = 32; off > 0; off >>= 1)
        acc += __shfl_down(acc, off, 64);
    if ((tid & 63) == 0) wsum[tid >> 6] = acc;
    __syncthreads();
    if (tid == 0)
        atomicAdd(out + plane,
                  (wsum[0] + wsum[1] + wsum[2] + wsum[3]) * (1.f / NPIX));
}

extern "C" void kernel_launch(void* const* d_in, const int* in_sizes, int n_in,
                              void* d_out, int out_size, void* d_ws, size_t ws_size,
                              hipStream_t stream) {
    const float* x = (const float*)d_in[0];
    float* out = (float*)d_out;
    zero_out<<<dim3(1), dim3(1024), 0, stream>>>(out);
    bp_kernel<<<dim3(16 * 64 * 4), dim3(256), 0, stream>>>(x, out);
}

// Round 5
// 40.536 us; speedup vs baseline: 1.1755x; 1.0551x over previous
//
#include <hip/hip_runtime.h>

#define H     128
#define W     128
#define HO    126
#define WO    126
#define NPIX  (HO * WO)          // 15876
#define CHUNKS 8
#define CROWS 16                 // output rows per chunk (last chunk: 14)
#define TROWS 18                 // max staged input rows
#define TSZ   (TROWS * W + 8)

__global__ __launch_bounds__(1024) void zero_out(float* __restrict__ out) {
    out[threadIdx.x] = 0.f;
}

// One block per (plane, 16-row chunk). 8192 blocks x 9.2 KB LDS ->
// 8 blocks/CU (32 waves), grid = exactly 4 full rounds of 2048.
__global__ __launch_bounds__(256, 8) void bp_kernel(const float* __restrict__ x,
                                                    float* __restrict__ out) {
    __shared__ float tile[TSZ];
    __shared__ float wsum[4];

    const int bid   = blockIdx.x;
    const int plane = bid >> 3;
    const int c     = bid & 7;
    const int orows = (c == 7) ? (HO - 7 * CROWS) : CROWS;   // 14 or 16
    const int irows = orows + 2;
    const int tid   = threadIdx.x;

    // ---- stage rows (linear, coalesced) ----
    const float4* src4 = (const float4*)(x + (size_t)plane * (H * W)) + (c * CROWS) * 32;
    float4* t4 = (float4*)tile;
    for (int i = tid; i < irows * 32; i += 256)
        t4[i] = src4[i];
    __syncthreads();

    float acc = 0.f;
    const int ng = orows * 32;          // 4-px groups, 32 per output row

#pragma unroll 1
    for (int g = tid; g < ng; g += 256) {
        const int y  = g >> 5;
        const int xq = g & 31;
        const int x0 = xq << 2;

        float r[3][6];
#pragma unroll
        for (int dr = 0; dr < 3; ++dr) {
            const float* rowp = &tile[(y + dr) * W + x0];
            const float4 a = *(const float4*)rowp;       // cols x0..x0+3
            const float2 b = *(const float2*)(rowp + 4); // cols x0+4,x0+5 (garbage at xq=31 -> masked px only)
            r[dr][0] = a.x; r[dr][1] = a.y; r[dr][2] = a.z; r[dr][3] = a.w;
            r[dr][4] = b.x; r[dr][5] = b.y;
        }

        float cs[6], cq[6], cm[6];
#pragma unroll
        for (int cc = 0; cc < 6; ++cc) {
            cs[cc] = r[0][cc] + r[1][cc] + r[2][cc];
            cq[cc] = fmaf(r[0][cc], r[0][cc], fmaf(r[1][cc], r[1][cc], r[2][cc] * r[2][cc]));
            cm[cc] = fmaxf(r[0][cc], fmaxf(r[1][cc], r[2][cc]));   // -> v_max3
        }

        float bnv[4];
#pragma unroll
        for (int k = 0; k < 4; ++k) {
            const float ctr  = r[1][k + 1];
            const float sum  = cs[k] + cs[k + 1] + cs[k + 2];
            const float ss   = cq[k] + cq[k + 1] + cq[k + 2];
            const float wmax = fmaxf(cm[k], fmaxf(cm[k + 1], cm[k + 2]));

            float d[8];
            d[0] = r[0][k]     - ctr;  d[1] = r[0][k + 1] - ctr;
            d[2] = r[0][k + 2] - ctr;  d[3] = r[1][k]     - ctr;
            d[4] = r[1][k + 2] - ctr;  d[5] = r[2][k]     - ctr;
            d[6] = r[2][k + 1] - ctr;  d[7] = r[2][k + 2] - ctr;

            const float sad = ((fabsf(d[0]) + fabsf(d[1])) + (fabsf(d[2]) + fabsf(d[3])))
                            + ((fabsf(d[4]) + fabsf(d[5])) + (fabsf(d[6]) + fabsf(d[7])));
            const float thr = sad * (1.f / 9.f);

            int bvi = (sad <= 0.f) ? 1 : 0;   // center tap: 0 >= thr
#pragma unroll
            for (int t = 0; t < 8; ++t)
                bvi += (d[t] >= thr) ? 1 : 0;
            const float bv = (float)bvi;

            const float var9 = fmaf(sum, -sum, 9.f * ss);                // 81*var
            const float sd9  = __builtin_amdgcn_sqrtf(fmaxf(var9, 0.f)); // 9*std
            const float nf   = fmaf(sum, -1.f / 2295.f, bv * (1.f / 255.f));
            bnv[k] = fmaf(nf, fmaf(sd9, 1.f / 9.f, -wmax), wmax);
        }

        // k=0,1 always in-bounds; k=2,3 only when xq<31 (WO=126=4*31+2)
        acc += bnv[0] + bnv[1];
        acc += (xq < 31) ? (bnv[2] + bnv[3]) : 0.f;
    }

    // ---- block reduction + atomic combine ----
#pragma unroll
    for (int off = 32; off > 0; off >>= 1)
        acc += __shfl_down(acc, off, 64);
    if ((tid & 63) == 0) wsum[tid >> 6] = acc;
    __syncthreads();
    if (tid == 0)
        atomicAdd(out + plane,
                  (wsum[0] + wsum[1] + wsum[2] + wsum[3]) * (1.f / NPIX));
}

extern "C" void kernel_launch(void* const* d_in, const int* in_sizes, int n_in,
                              void* d_out, int out_size, void* d_ws, size_t ws_size,
                              hipStream_t stream) {
    const float* x = (const float*)d_in[0];
    float* out = (float*)d_out;
    zero_out<<<dim3(1), dim3(1024), 0, stream>>>(out);
    bp_kernel<<<dim3(16 * 64 * CHUNKS), dim3(256), 0, stream>>>(x, out);
}